// Round 3
// baseline (357.185 us; speedup 1.0000x reference)
//
#include <hip/hip_runtime.h>
#include <hip/hip_bf16.h>
#include <math.h>
#include <float.h>

#ifndef M_PI
#define M_PI 3.14159265358979323846
#endif

// Problem constants
#define NBANDS 160      // B*NB = 32*5
#define RR 96           // rows per band
#define TT 2048         // time samples
#define NTRIL 4560      // 96*95/2
#define A_ELEMS ((size_t)NBANDS * RR * RR)
#define NBIN 16384
#define MAXCAND 512

#define KS 8
#define CHUNK 256
#define BKS 64
#define GPITCH 72

// XOR bank swizzle for the FFT kernel
#define PHI(L) ((L) ^ (((L) >> 5) & 31))

typedef float  f32x4  __attribute__((ext_vector_type(4)));
typedef __bf16 bf16x8 __attribute__((ext_vector_type(8)));
typedef __bf16 bf16x4 __attribute__((ext_vector_type(4)));

// ---------- block reductions (256 threads = 4 waves) ----------
__device__ inline void blockReduceSum4(double v0, double v1, double v2, double v3,
                                       double* sred, double out[4]) {
    for (int off = 32; off > 0; off >>= 1) {
        v0 += __shfl_down(v0, off, 64);
        v1 += __shfl_down(v1, off, 64);
        v2 += __shfl_down(v2, off, 64);
        v3 += __shfl_down(v3, off, 64);
    }
    int lane = threadIdx.x & 63, wid = threadIdx.x >> 6;
    if (lane == 0) {
        sred[wid * 4 + 0] = v0; sred[wid * 4 + 1] = v1;
        sred[wid * 4 + 2] = v2; sred[wid * 4 + 3] = v3;
    }
    __syncthreads();
    if (threadIdx.x < 4) {
        double r = sred[threadIdx.x] + sred[4 + threadIdx.x]
                 + sred[8 + threadIdx.x] + sred[12 + threadIdx.x];
        sred[16 + threadIdx.x] = r;
    }
    __syncthreads();
    out[0] = sred[16]; out[1] = sred[17]; out[2] = sred[18]; out[3] = sred[19];
    __syncthreads();
}

__device__ inline void blockReduceSum2(double v0, double v1,
                                       double* sred, double out[2]) {
    for (int off = 32; off > 0; off >>= 1) {
        v0 += __shfl_down(v0, off, 64);
        v1 += __shfl_down(v1, off, 64);
    }
    int lane = threadIdx.x & 63, wid = threadIdx.x >> 6;
    if (lane == 0) { sred[wid * 2 + 0] = v0; sred[wid * 2 + 1] = v1; }
    __syncthreads();
    if (threadIdx.x < 2) {
        double r = sred[threadIdx.x] + sred[2 + threadIdx.x]
                 + sred[4 + threadIdx.x] + sred[6 + threadIdx.x];
        sred[8 + threadIdx.x] = r;
    }
    __syncthreads();
    out[0] = sred[8]; out[1] = sred[9];
    __syncthreads();
}

__device__ inline void blockReduceMax4(double v0, double v1, double v2, double v3,
                                       double* sred, double out[4]) {
    for (int off = 32; off > 0; off >>= 1) {
        v0 = fmax(v0, __shfl_down(v0, off, 64));
        v1 = fmax(v1, __shfl_down(v1, off, 64));
        v2 = fmax(v2, __shfl_down(v2, off, 64));
        v3 = fmax(v3, __shfl_down(v3, off, 64));
    }
    int lane = threadIdx.x & 63, wid = threadIdx.x >> 6;
    if (lane == 0) {
        sred[wid * 4 + 0] = v0; sred[wid * 4 + 1] = v1;
        sred[wid * 4 + 2] = v2; sred[wid * 4 + 3] = v3;
    }
    __syncthreads();
    if (threadIdx.x < 4) {
        double r = fmax(fmax(sred[threadIdx.x], sred[4 + threadIdx.x]),
                        fmax(sred[8 + threadIdx.x], sred[12 + threadIdx.x]));
        sred[16 + threadIdx.x] = r;
    }
    __syncthreads();
    out[0] = sred[16]; out[1] = sred[17]; out[2] = sred[18]; out[3] = sred[19];
    __syncthreads();
}

// ---------- K0: twiddle table  tw[k] = exp(-2*pi*i*k/2048), k<1024 (fp32) ----------
__global__ void twiddle_kernel(float* tw) {
    int k = blockIdx.x * blockDim.x + threadIdx.x;
    if (k < 1024) {
        double ang = -2.0 * M_PI * (double)k / 2048.0;
        tw[2 * k]     = (float)cos(ang);
        tw[2 * k + 1] = (float)sin(ang);
    }
}

// single-FFT butterfly on register arrays yr/yi
#define BFLY1(yr, yi, r1, r2, WR, WI) do { \
    float _wr = (WR), _wi = (WI); \
    float _tr = _wr * yr[r2] - _wi * yi[r2]; \
    float _ti = _wr * yi[r2] + _wi * yr[r2]; \
    yr[r2] = yr[r1] - _tr; yi[r2] = yi[r1] - _ti; \
    yr[r1] += _tr; yi[r1] += _ti; } while (0)

__device__ inline void fft_g1(float (&yr)[8], float (&yi)[8]) {
    const float RC = 0.70710678f;
    BFLY1(yr, yi, 0, 1, 1.0f, 0.0f); BFLY1(yr, yi, 2, 3, 1.0f, 0.0f);
    BFLY1(yr, yi, 4, 5, 1.0f, 0.0f); BFLY1(yr, yi, 6, 7, 1.0f, 0.0f);
    BFLY1(yr, yi, 0, 2, 1.0f, 0.0f); BFLY1(yr, yi, 1, 3, 0.0f, -1.0f);
    BFLY1(yr, yi, 4, 6, 1.0f, 0.0f); BFLY1(yr, yi, 5, 7, 0.0f, -1.0f);
    BFLY1(yr, yi, 0, 4, 1.0f, 0.0f); BFLY1(yr, yi, 1, 5, RC, -RC);
    BFLY1(yr, yi, 2, 6, 0.0f, -1.0f); BFLY1(yr, yi, 3, 7, -RC, -RC);
}

__device__ inline void fft_g2(float (&yr)[8], float (&yi)[8],
                              const float2* __restrict__ twv, int oo) {
    float2 w0 = twv[oo << 7];
    BFLY1(yr, yi, 0, 1, w0.x, w0.y); BFLY1(yr, yi, 2, 3, w0.x, w0.y);
    BFLY1(yr, yi, 4, 5, w0.x, w0.y); BFLY1(yr, yi, 6, 7, w0.x, w0.y);
    float2 wa = twv[oo << 6];
    float2 wb = twv[(oo + 8) << 6];
    BFLY1(yr, yi, 0, 2, wa.x, wa.y); BFLY1(yr, yi, 1, 3, wb.x, wb.y);
    BFLY1(yr, yi, 4, 6, wa.x, wa.y); BFLY1(yr, yi, 5, 7, wb.x, wb.y);
    float2 wc0 = twv[oo << 5], wc1 = twv[(oo + 8) << 5];
    float2 wc2 = twv[(oo + 16) << 5], wc3 = twv[(oo + 24) << 5];
    BFLY1(yr, yi, 0, 4, wc0.x, wc0.y);
    BFLY1(yr, yi, 1, 5, wc1.x, wc1.y);
    BFLY1(yr, yi, 2, 6, wc2.x, wc2.y);
    BFLY1(yr, yi, 3, 7, wc3.x, wc3.y);
}

__device__ inline void fft_g3(float (&yr)[8], float (&yi)[8],
                              const float2* __restrict__ twv, int O3) {
    float2 w0 = twv[O3 << 4];
    float2 wa = twv[O3 << 3];
    float2 wb = twv[(O3 + 64) << 3];
    BFLY1(yr, yi, 0, 1, w0.x, w0.y); BFLY1(yr, yi, 2, 3, w0.x, w0.y);
    BFLY1(yr, yi, 4, 5, w0.x, w0.y); BFLY1(yr, yi, 6, 7, w0.x, w0.y);
    BFLY1(yr, yi, 0, 2, wa.x, wa.y); BFLY1(yr, yi, 1, 3, wb.x, wb.y);
    BFLY1(yr, yi, 4, 6, wa.x, wa.y); BFLY1(yr, yi, 5, 7, wb.x, wb.y);
}

__device__ inline void fft_g4(float (&yr)[8], float (&yi)[8],
                              const float2* __restrict__ twv, int t) {
    float2 w0 = twv[t << 2];
    float2 wa = twv[t << 1];
    float2 wb = twv[(t + 256) << 1];
    BFLY1(yr, yi, 0, 1, w0.x, w0.y); BFLY1(yr, yi, 2, 3, w0.x, w0.y);
    BFLY1(yr, yi, 4, 5, w0.x, w0.y); BFLY1(yr, yi, 6, 7, w0.x, w0.y);
    BFLY1(yr, yi, 0, 2, wa.x, wa.y); BFLY1(yr, yi, 1, 3, wb.x, wb.y);
    BFLY1(yr, yi, 4, 6, wa.x, wa.y); BFLY1(yr, yi, 5, 7, wb.x, wb.y);
    float2 wf0 = twv[t], wf1 = twv[t + 256];
    float2 wf2 = twv[t + 512], wf3 = twv[t + 768];
    BFLY1(yr, yi, 0, 4, wf0.x, wf0.y);
    BFLY1(yr, yi, 1, 5, wf1.x, wf1.y);
    BFLY1(yr, yi, 2, 6, wf2.x, wf2.y);
    BFLY1(yr, yi, 3, 7, wf3.x, wf3.y);
}

// exchange-pattern macros (operate on bufA/bufB, thread-local indices)
#define WR_P1(yr, yi) do { _Pragma("unroll") \
    for (int j = 0; j < 8; j++) { int P = PHI(8 * t + j); bufA[P] = yr[j]; bufB[P] = yi[j]; } } while (0)
#define RD_P1(yr, yi) do { _Pragma("unroll") \
    for (int k = 0; k < 8; k++) { int P = PHI(64 * bb64 + 8 * k + oo); yr[k] = bufA[P]; yi[k] = bufB[P]; } } while (0)
#define WR_P2(yr, yi) do { _Pragma("unroll") \
    for (int k = 0; k < 8; k++) { int P = PHI(64 * bb64 + 8 * k + oo); bufA[P] = yr[k]; bufB[P] = yi[k]; } } while (0)
#define RD_P2(yr, yi) do { _Pragma("unroll") \
    for (int s = 0; s < 2; s++) { int B3 = Wq + 4 * s; _Pragma("unroll") \
      for (int k = 0; k < 4; k++) { int P = PHI(256 * B3 + 64 * k + O3); yr[4 * s + k] = bufA[P]; yi[4 * s + k] = bufB[P]; } } } while (0)
#define WR_P3(yr, yi) do { _Pragma("unroll") \
    for (int s = 0; s < 2; s++) { int B3 = Wq + 4 * s; _Pragma("unroll") \
      for (int k = 0; k < 4; k++) { int P = PHI(256 * B3 + 64 * k + O3); bufA[P] = yr[4 * s + k]; bufB[P] = yi[4 * s + k]; } } } while (0)
#define RD_P3(yr, yi) do { _Pragma("unroll") \
    for (int k = 0; k < 8; k++) { int P = PHI(256 * k + t); yr[k] = bufA[P]; yi[k] = bufB[P]; } } while (0)
#define WR_F(yr, yi) do { _Pragma("unroll") \
    for (int k = 0; k < 8; k++) { int P = PHI(256 * k + t); bufA[P] = yr[k]; bufB[P] = yi[k]; } } while (0)
// power-spectrum, in place: yr[k] <- psa[k], yi[k] <- psb[k]
#define PS_INPLACE(yr, yi, lA, lB) do { _Pragma("unroll") \
    for (int k = 0; k < 8; k++) { \
        int q = (2048 - t - 256 * k) & 2047; int P = PHI(q); \
        float prr = bufA[P], pii = bufB[P]; \
        float sr = yr[k] + prr, di = yi[k] - pii; \
        float si = yi[k] + pii, dr = yr[k] - prr; \
        float pa = 0.25f * (sr * sr + di * di); \
        float pb = 0.25f * (si * si + dr * dr); \
        lA += pa; lB += pb; yr[k] = pa; yi[k] = pb; } } while (0)

// ---------- K1: per-row stats + two fp32 radix-8 FFTs through ONE LDS buffer ----------
// 4 rows per block (2 complex FFTs). Exchanges serialized per FFT through a
// single 16.4 KB bufA/bufB pair (8 blocks/CU); each FFT's butterflies overlap
// the other FFT's ds_writes. PS computed in place (yr<-psa) to keep VGPR<=64.
__global__ __launch_bounds__(256, 8) void rowstat_fft_kernel(
    const float* __restrict__ wc, const float* __restrict__ tw,
    double* __restrict__ rowstats)
{
    __shared__ float bufA[TT];
    __shared__ float bufB[TT];
    __shared__ double sred[24];
    __shared__ double statout[12];

    int t = threadIdx.x;
    int g0 = blockIdx.x * 4;

    int band = g0 / RR, r0 = g0 % RR;      // 96 % 4 == 0: all 4 rows same band
    int b = band / 5, nb = band % 5;
    size_t base0 = ((size_t)(b * RR + r0) * 5 + nb) * TT;
    const size_t RSTR = (size_t)5 * TT;
    const float2* twv = (const float2*)tw;

    float r2b[8], i2b[8];
    float s0 = 0.f, s1 = 0.f, s2 = 0.f, s3 = 0.f;
    float q0 = 0.f, q1 = 0.f, q2 = 0.f, q3 = 0.f;
    float m0 = 0.f, m1 = 0.f, m2 = 0.f, m3 = 0.f;
#pragma unroll
    for (int c = 0; c < 8; c++) {
        int i = t + c * 256;
        float a0 = wc[base0 + i];
        float a1 = wc[base0 + RSTR + i];
        float a2 = wc[base0 + 2 * RSTR + i];
        float a3 = wc[base0 + 3 * RSTR + i];
        int P = PHI(i);
        bufA[P] = a0; bufB[P] = a1;        // FFT1 = rows 0/1
        r2b[c] = a2; i2b[c] = a3;          // FFT2 staged in regs
        s0 += a0; s1 += a1; s2 += a2; s3 += a3;
        q0 = fmaf(a0, a0, q0); q1 = fmaf(a1, a1, q1);
        q2 = fmaf(a2, a2, q2); q3 = fmaf(a3, a3, q3);
        m0 = fmaxf(m0, fabsf(a0)); m1 = fmaxf(m1, fabsf(a1));
        m2 = fmaxf(m2, fabsf(a2)); m3 = fmaxf(m3, fabsf(a3));
    }
    __syncthreads();

    {
        double S[4], Q[4], M[4];
        blockReduceSum4((double)s0, (double)s1, (double)s2, (double)s3, sred, S);
        blockReduceSum4((double)q0, (double)q1, (double)q2, (double)q3, sred, Q);
        blockReduceMax4((double)m0, (double)m1, (double)m2, (double)m3, sred, M);
        if (t == 0) {
            statout[0] = S[0]; statout[1] = S[1]; statout[2] = S[2]; statout[3] = S[3];
            statout[4] = Q[0]; statout[5] = Q[1]; statout[6] = Q[2]; statout[7] = Q[3];
            statout[8] = M[0]; statout[9] = M[1]; statout[10] = M[2]; statout[11] = M[3];
        }
    }
    // (blockReduce ends with __syncthreads; bufA/B stable since the c-loop)

    float yr1[8], yi1[8], yr2[8], yi2[8];

    // ---- bit-reversal load, FFT1 then FFT2 through the same buffer ----
#pragma unroll
    for (int j = 0; j < 8; j++) {
        int p = 8 * t + j;
        int L = (int)(__brev((unsigned)p) >> 21);
        int P = PHI(L);
        yr1[j] = bufA[P]; yi1[j] = bufB[P];
    }
    __syncthreads();
#pragma unroll
    for (int c = 0; c < 8; c++) {
        int P = PHI(t + c * 256);
        bufA[P] = r2b[c]; bufB[P] = i2b[c];
    }
    fft_g1(yr1, yi1);                      // overlaps FFT2 ds_writes
    __syncthreads();
#pragma unroll
    for (int j = 0; j < 8; j++) {
        int p = 8 * t + j;
        int L = (int)(__brev((unsigned)p) >> 21);
        int P = PHI(L);
        yr2[j] = bufA[P]; yi2[j] = bufB[P];
    }
    fft_g1(yr2, yi2);

    int oo = t & 7;
    int bb64 = 4 * ((t >> 3) & 7) + (t >> 6);
    int O3 = t & 63, Wq = t >> 6;

    // ---- exchange P1 + G2 ----
    __syncthreads();
    WR_P1(yr1, yi1);
    __syncthreads();
    RD_P1(yr1, yi1);
    __syncthreads();
    WR_P1(yr2, yi2);
    fft_g2(yr1, yi1, twv, oo);             // overlaps FFT2 ds_writes
    __syncthreads();
    RD_P1(yr2, yi2);
    fft_g2(yr2, yi2, twv, oo);

    // ---- exchange P2 + G3 ----
    __syncthreads();
    WR_P2(yr1, yi1);
    __syncthreads();
    RD_P2(yr1, yi1);
    __syncthreads();
    WR_P2(yr2, yi2);
    fft_g3(yr1, yi1, twv, O3);
    __syncthreads();
    RD_P2(yr2, yi2);
    fft_g3(yr2, yi2, twv, O3);

    // ---- exchange P3 + G4 ----
    __syncthreads();
    WR_P3(yr1, yi1);
    __syncthreads();
    RD_P3(yr1, yi1);
    __syncthreads();
    WR_P3(yr2, yi2);
    fft_g4(yr1, yi1, twv, t);
    __syncthreads();
    RD_P3(yr2, yi2);
    fft_g4(yr2, yi2, twv, t);

    // ---- power spectra (in place), serialized through the buffer ----
    float la = 0.f, lb = 0.f, lc = 0.f, ld = 0.f;
    __syncthreads();
    WR_F(yr1, yi1);
    __syncthreads();
    PS_INPLACE(yr1, yi1, la, lb);          // yr1/yi1 now hold psa1/psb1
    __syncthreads();
    WR_F(yr2, yi2);
    __syncthreads();
    PS_INPLACE(yr2, yi2, lc, ld);          // yr2/yi2 now hold psa2/psb2

    double SS[4];
    blockReduceSum4((double)la, (double)lb, (double)lc, (double)ld, sred, SS);
    // half-spectrum corrections: thread 0 holds freq0 (k=0) and freq1024 (k=4)
    __shared__ float bcast[8];
    if (t == 0) {
        bcast[0] = yr1[0]; bcast[1] = yr1[4];
        bcast[2] = yi1[0]; bcast[3] = yi1[4];
        bcast[4] = yr2[0]; bcast[5] = yr2[4];
        bcast[6] = yi2[0]; bcast[7] = yi2[4];
    }
    __syncthreads();
    double Sa = 0.5 * (SS[0] + (double)bcast[0] - (double)bcast[1]);
    double Sb = 0.5 * (SS[1] + (double)bcast[2] - (double)bcast[3]);
    double Sc = 0.5 * (SS[2] + (double)bcast[4] - (double)bcast[5]);
    double Sd = 0.5 * (SS[3] + (double)bcast[6] - (double)bcast[7]);
    if (Sa == 0.0) Sa = 1.0;
    if (Sb == 0.0) Sb = 1.0;
    if (Sc == 0.0) Sc = 1.0;
    if (Sd == 0.0) Sd = 1.0;
    float invSa = (float)(1.0 / Sa), invSb = (float)(1.0 / Sb);
    float invSc = (float)(1.0 / Sc), invSd = (float)(1.0 / Sd);

    float ea = 0.f, eb = 0.f, ec = 0.f, ed = 0.f;
#pragma unroll
    for (int k = 0; k < 8; k++) {
        float pa = yr1[k] * invSa;
        float pb = yi1[k] * invSb;
        float pc = yr2[k] * invSc;
        float pd = yi2[k] * invSd;
        ea += pa * __logf(pa + 1e-10f);
        eb += pb * __logf(pb + 1e-10f);
        ec += pc * __logf(pc + 1e-10f);
        ed += pd * __logf(pd + 1e-10f);
    }
    double EE[4];
    blockReduceSum4((double)ea, (double)eb, (double)ec, (double)ed, sred, EE);

    if (t == 0) {
        float pa0 = yr1[0] * invSa, pa4 = yr1[4] * invSa;
        float pb0 = yi1[0] * invSb, pb4 = yi1[4] * invSb;
        float pc0 = yr2[0] * invSc, pc4 = yr2[4] * invSc;
        float pd0 = yi2[0] * invSd, pd4 = yi2[4] * invSd;
        double TA = 0.5 * (EE[0] + (double)(pa0 * __logf(pa0 + 1e-10f))
                                 - (double)(pa4 * __logf(pa4 + 1e-10f)));
        double TB = 0.5 * (EE[1] + (double)(pb0 * __logf(pb0 + 1e-10f))
                                 - (double)(pb4 * __logf(pb4 + 1e-10f)));
        double TC = 0.5 * (EE[2] + (double)(pc0 * __logf(pc0 + 1e-10f))
                                 - (double)(pc4 * __logf(pc4 + 1e-10f)));
        double TD = 0.5 * (EE[3] + (double)(pd0 * __logf(pd0 + 1e-10f))
                                 - (double)(pd4 * __logf(pd4 + 1e-10f)));
        double TAs[4] = {TA, TB, TC, TD};
#pragma unroll
        for (int rix = 0; rix < 4; rix++) {
            double SUM = statout[rix], SQ = statout[4 + rix], MX = statout[8 + rix];
            double mean = SUM / (double)TT;
            double nsq = SQ - (double)TT * mean * mean; if (nsq < 0) nsq = 0;
            double nrm = sqrt(nsq);
            double* w = rowstats + (size_t)(g0 + rix) * 6;
            w[0] = mean; w[1] = (nrm == 0.0 ? 1.0 : nrm); w[2] = sqrt(nsq / 2047.0);
            w[3] = SQ;   w[4] = MX;                       w[5] = -TAs[rix];
        }
    }
}

// ---------- K2a: zero the Gram staging region (fallback path only) ----------
__global__ void zero_kernel(float4* __restrict__ p, int n4) {
    int i = blockIdx.x * blockDim.x + threadIdx.x;
    if (i < n4) p[i] = make_float4(0.f, 0.f, 0.f, 0.f);
}

// ---------- K2b: MFMA Gram (hi/lo bf16 split, fp32 MFMA accum) ----------
template <bool USE_PART>
__global__ __launch_bounds__(384) void gram_mfma_kernel(
    const float* __restrict__ wc, float* __restrict__ G)
{
    __shared__ __attribute__((aligned(16))) __bf16 sh_hi[RR][GPITCH];
    __shared__ __attribute__((aligned(16))) __bf16 sh_lo[RR][GPITCH];

    int bid = blockIdx.x;
    int band = bid / KS, chunk = bid % KS;
    int b = band / 5, nb = band % 5;
    size_t bandbase = ((size_t)b * RR * 5 + nb) * TT + (size_t)chunk * CHUNK;

    int t = threadIdx.x;
    int wave = t >> 6, lane = t & 63;
    int m16 = lane & 15, quad = lane >> 4;
    int arow = wave * 16 + m16;

    f32x4 acc[6];
#pragma unroll
    for (int ct = 0; ct < 6; ct++) acc[ct] = (f32x4){0.f, 0.f, 0.f, 0.f};

    for (int stage = 0; stage < CHUNK / BKS; stage++) {
        int k0 = stage * BKS;
#pragma unroll
        for (int i = 0; i < 4; i++) {
            int gid = t + i * 384;          // 0..1535
            int row = gid >> 4, c4 = gid & 15;
            float4 v = *(const float4*)(wc + bandbase + (size_t)row * (5 * TT) + k0 + c4 * 4);
            __bf16 h0 = (__bf16)v.x, h1 = (__bf16)v.y, h2 = (__bf16)v.z, h3 = (__bf16)v.w;
            __bf16 l0 = (__bf16)(v.x - (float)h0);
            __bf16 l1 = (__bf16)(v.y - (float)h1);
            __bf16 l2 = (__bf16)(v.z - (float)h2);
            __bf16 l3 = (__bf16)(v.w - (float)h3);
            *(bf16x4*)&sh_hi[row][c4 * 4] = (bf16x4){h0, h1, h2, h3};
            *(bf16x4*)&sh_lo[row][c4 * 4] = (bf16x4){l0, l1, l2, l3};
        }
        __syncthreads();
#pragma unroll
        for (int ks = 0; ks < BKS / 32; ks++) {
            int ko = ks * 32 + quad * 8;
            bf16x8 ah = *(const bf16x8*)&sh_hi[arow][ko];
            bf16x8 al = *(const bf16x8*)&sh_lo[arow][ko];
#pragma unroll
            for (int ct = 0; ct < 6; ct++) {
                int brow = ct * 16 + m16;
                bf16x8 bh = *(const bf16x8*)&sh_hi[brow][ko];
                bf16x8 bl = *(const bf16x8*)&sh_lo[brow][ko];
                acc[ct] = __builtin_amdgcn_mfma_f32_16x16x32_bf16(ah, bh, acc[ct], 0, 0, 0);
                acc[ct] = __builtin_amdgcn_mfma_f32_16x16x32_bf16(ah, bl, acc[ct], 0, 0, 0);
                acc[ct] = __builtin_amdgcn_mfma_f32_16x16x32_bf16(al, bh, acc[ct], 0, 0, 0);
            }
        }
        __syncthreads();
    }

    if (USE_PART) {
        float* Gp = G + (size_t)bid * (RR * RR);   // per-chunk partial tile
#pragma unroll
        for (int ct = 0; ct < 6; ct++) {
#pragma unroll
            for (int r = 0; r < 4; r++) {
                int grow = wave * 16 + quad * 4 + r;
                int gcol = ct * 16 + m16;
                Gp[grow * RR + gcol] = acc[ct][r];
            }
        }
    } else {
        float* Gb = G + (size_t)band * (RR * RR);
#pragma unroll
        for (int ct = 0; ct < 6; ct++) {
#pragma unroll
            for (int r = 0; r < 4; r++) {
                int grow = wave * 16 + quad * 4 + r;
                int gcol = ct * 16 + m16;
                atomicAdd(&Gb[grow * RR + gcol], acc[ct][r]);
            }
        }
    }
}

// ---------- K3: fused per-band finalize ----------
// normalize (+partial sum) -> C in LDS -> histogram quantile -> masked A write
// -> ballot bitmask graph props -> MLP -> F.
template <bool USE_PART>
__global__ __launch_bounds__(256) void band_finalize_kernel(
    const float* __restrict__ Gsrc, const double* __restrict__ rowstats,
    const int* __restrict__ community,
    const float* __restrict__ W1, const float* __restrict__ b1,
    const float* __restrict__ W2, const float* __restrict__ b2,
    float* __restrict__ A_out, float* __restrict__ F_out)
{
    __shared__ float Cs[RR][RR];               // 36 KB
    __shared__ int hist[NBIN];                 // 64 KB
    __shared__ int chunkv[256];
    __shared__ float cand[MAXCAND];
    __shared__ int ctrl[4];
    __shared__ double mean_s[RR], inv_s[RR];
    __shared__ int comm_s[RR];
    __shared__ unsigned long long msk[RR][2];
    __shared__ int deg[RR];
    __shared__ double sred[24];
    __shared__ double feat[11];
    __shared__ double hmlp[32];
    __shared__ double thr_s;

    int band = blockIdx.x, t = threadIdx.x;
    const double* rsb = rowstats + (size_t)band * RR * 6;
    if (t < RR) {
        mean_s[t] = rsb[t * 6 + 0];
        inv_s[t]  = 1.0 / rsb[t * 6 + 1];
        comm_s[t] = community[t];
    }
    for (int i = t; i < NBIN; i += 256) hist[i] = 0;
    if (t == 0) ctrl[3] = 0;
    __syncthreads();

    // normalize (+ KS-way partial sum) into LDS, histogram tril on the fly
    for (int idx = t; idx < RR * RR; idx += 256) {
        int i = idx / RR, j = idx % RR;
        float g;
        if (USE_PART) {
            const float* p = Gsrc + (size_t)band * KS * (RR * RR) + idx;
            float acc = 0.f;
#pragma unroll
            for (int c = 0; c < KS; c++) acc += p[(size_t)c * (RR * RR)];
            g = acc;
        } else {
            g = Gsrc[(size_t)band * (RR * RR) + idx];
        }
        double cd = ((double)g - (double)TT * mean_s[i] * mean_s[j]) * (inv_s[i] * inv_s[j]);
        if (i == j) cd = 0.0;
        float cf = (float)cd;
        Cs[i][j] = cf;
        if (j < i) {
            float val = fabsf(cf);
            int bin = (int)(val * (float)NBIN);
            bin = bin > (NBIN - 1) ? (NBIN - 1) : bin;
            atomicAdd(&hist[bin], 1);
        }
    }
    __syncthreads();

    int cs = 0;
    for (int i = 0; i < 64; i++) cs += hist[t * 64 + i];
    chunkv[t] = cs;
    __syncthreads();

    if (t == 0) {
        int r0 = 3647, r1 = 3648;
        int cum = 0, c0 = 0;
        while (c0 < 256 && cum + chunkv[c0] <= r0) { cum += chunkv[c0]; c0++; }
        int bin = c0 * 64, cb = cum;
        while (cb + hist[bin] <= r0) { cb += hist[bin]; bin++; }
        int B0 = bin, cumB0 = cb;
        int bin1 = bin, cb1 = cb;
        while (cb1 + hist[bin1] <= r1) { cb1 += hist[bin1]; bin1++; }
        ctrl[0] = B0; ctrl[1] = bin1; ctrl[2] = cumB0;
    }
    __syncthreads();

    int B0 = ctrl[0], B1 = ctrl[1];
    for (int idx = t; idx < RR * RR; idx += 256) {
        int i = idx / RR, j = idx % RR;
        if (j < i) {
            float val = fabsf(Cs[i][j]);
            int bin = (int)(val * (float)NBIN);
            bin = bin > (NBIN - 1) ? (NBIN - 1) : bin;
            if (bin >= B0 && bin <= B1) {
                int k = atomicAdd(&ctrl[3], 1);
                if (k < MAXCAND) cand[k] = val;
            }
        }
    }
    __syncthreads();

    if (t == 0) {
        int n = ctrl[3]; if (n > MAXCAND) n = MAXCAND;
        for (int i = 1; i < n; i++) {
            float key = cand[i]; int j = i - 1;
            while (j >= 0 && cand[j] > key) { cand[j + 1] = cand[j]; j--; }
            cand[j + 1] = key;
        }
        int r0 = 3647 - ctrl[2];
        int r1 = 3648 - ctrl[2];
        double v0 = (double)cand[r0], v1 = (double)cand[r1];
        thr_s = v0 + 0.2 * (v1 - v0);       // pos = 0.8*(4560-1) = 3647.2
    }
    __syncthreads();
    double thr = thr_s;

    // masked A write (single pass, coalesced)
    float* Ab = A_out + (size_t)band * (RR * RR);
    for (int idx = t; idx < RR * RR; idx += 256) {
        float cf = Cs[idx / RR][idx % RR];
        bool keep = ((double)fabsf(cf) >= thr);
        Ab[idx] = keep ? cf : 0.f;
    }

    // adjacency bitmasks via ballot: wave w handles rows w, w+4, ...
    int lane = t & 63, wid = t >> 6;
    for (int i = wid; i < RR; i += 4) {
        float vlo = Cs[i][lane];
        bool klo = ((double)fabsf(vlo) >= thr) && (vlo != 0.f);
        unsigned long long blo = __ballot(klo);
        float vhi = Cs[i][64 + (lane & 31)];
        bool khi = (lane < 32) && ((double)fabsf(vhi) >= thr) && (vhi != 0.f);
        unsigned long long bhi = __ballot(khi) & 0xffffffffull;
        if (lane == 0) {
            msk[i][0] = blo; msk[i][1] = bhi;
            deg[i] = __popcll(blo) + __popcll(bhi);
        }
    }
    __syncthreads();

    double triord = 0, ein = 0, expin = 0;
    for (int idx = t; idx < RR * RR; idx += 256) {
        int i = idx / RR, j = idx % RR;
        unsigned long long mi0 = msk[i][0], mi1 = msk[i][1];
        bool bij = (((j < 64) ? (mi0 >> j) : (mi1 >> (j - 64))) & 1ull) != 0;
        if (bij)
            triord += (double)(__popcll(mi0 & msk[j][0]) +
                               __popcll(mi1 & msk[j][1]));
        if (i != j && comm_s[i] == comm_s[j]) {
            ein += bij ? 1.0 : 0.0;
            expin += (double)deg[i] * (double)deg[j];
        }
    }
    double dv = (t < RR) ? (double)deg[t] : 0.0;
    double R1[4], R2[4], R3[2];
    blockReduceSum4(triord, ein, expin, dv, sred, R1);
    blockReduceSum4((t < RR) ? dv * (dv - 1.0) : 0.0,
                    (t < RR) ? rsb[t * 6 + 0] : 0.0,
                    (t < RR) ? rsb[t * 6 + 2] : 0.0,
                    (t < RR) ? rsb[t * 6 + 3] : 0.0, sred, R2);
    blockReduceSum2((t < RR) ? rsb[t * 6 + 4] : 0.0,
                    (t < RR) ? rsb[t * 6 + 5] : 0.0, sred, R3);
    double TRI = R1[0], EIN = R1[1], EXPIN = R1[2], DEGS = R1[3];
    double POSS2 = R2[0], N0 = R2[1], N1 = R2[2], N2 = R2[3];
    double N3 = R3[0], N4 = R3[1];

    if (t == 0) {
        double ne = 0.5 * DEGS;
        feat[0] = N0 / (double)RR;
        feat[1] = N1 / (double)RR;
        feat[2] = N2 / (double)RR;
        feat[3] = N3 / (double)RR;
        feat[4] = N4 / (double)RR;
        feat[5] = ne;
        feat[6] = ne / (double)NTRIL;
        feat[7] = DEGS / (double)RR;
        double tri = TRI / 6.0, poss = POSS2 * 0.5;
        feat[8] = (poss > 0.0) ? tri / poss : 0.0;
        feat[9] = ((double)RR + DEGS) / ((double)RR * (double)(RR - 1));
        double m2 = DEGS;
        feat[10] = (m2 > 0.0) ? (EIN - EXPIN / m2) / m2 : 0.0;
    }
    __syncthreads();

    if (t < 32) {
        double a = (double)b1[t];
        for (int k = 0; k < 11; k++) a += (double)W1[t * 11 + k] * feat[k];
        hmlp[t] = (a > 0.0) ? a : 0.0;
    }
    __syncthreads();
    if (t < 64) {
        double a = (double)b2[t];
        for (int j = 0; j < 32; j++) a += (double)W2[t * 32 + j] * hmlp[j];
        F_out[(size_t)band * 64 + t] = (float)a;
    }
}

extern "C" void kernel_launch(void* const* d_in, const int* in_sizes, int n_in,
                              void* d_out, int out_size, void* d_ws, size_t ws_size,
                              hipStream_t stream) {
    const float* wc        = (const float*)d_in[0];
    // d_in[1] frequency_bands: unused by the reference math
    const int*   community = (const int*)d_in[2];
    const float* W1        = (const float*)d_in[3];
    const float* b1        = (const float*)d_in[4];
    const float* W2        = (const float*)d_in[5];
    const float* b2        = (const float*)d_in[6];

    float* A_out = (float*)d_out;
    float* F_out = A_out + A_ELEMS;

    // workspace layout:
    //   tw        @ 0        (8192 B)
    //   rowstats  @ 8192     (15360*6*8 = 737280 B)
    //   Gpart     @ 747520   (160*8*9216*4 = 47185920 B)  [if ws is big enough]
    char* ws = (char*)d_ws;
    float*  tw       = (float*)ws;
    double* rowstats = (double*)(ws + 8192);
    const size_t PART_OFF   = 747520;
    const size_t PART_BYTES = (size_t)NBANDS * KS * RR * RR * sizeof(float);
    float* Gpart = (float*)(ws + PART_OFF);
    bool use_part = (ws_size >= PART_OFF + PART_BYTES);

    hipLaunchKernelGGL(twiddle_kernel, dim3(4), dim3(256), 0, stream, tw);
    hipLaunchKernelGGL(rowstat_fft_kernel, dim3(NBANDS * RR / 4), dim3(256), 0, stream,
                       wc, tw, rowstats);
    if (use_part) {
        hipLaunchKernelGGL(HIP_KERNEL_NAME(gram_mfma_kernel<true>),
                           dim3(NBANDS * KS), dim3(384), 0, stream, wc, Gpart);
        hipLaunchKernelGGL(HIP_KERNEL_NAME(band_finalize_kernel<true>),
                           dim3(NBANDS), dim3(256), 0, stream,
                           Gpart, rowstats, community, W1, b1, W2, b2, A_out, F_out);
    } else {
        int n4 = (int)(A_ELEMS / 4);       // 368640
        hipLaunchKernelGGL(zero_kernel, dim3((n4 + 255) / 256), dim3(256), 0, stream,
                           (float4*)A_out, n4);
        hipLaunchKernelGGL(HIP_KERNEL_NAME(gram_mfma_kernel<false>),
                           dim3(NBANDS * KS), dim3(384), 0, stream, wc, A_out);
        hipLaunchKernelGGL(HIP_KERNEL_NAME(band_finalize_kernel<false>),
                           dim3(NBANDS), dim3(256), 0, stream,
                           A_out, rowstats, community, W1, b1, W2, b2, A_out, F_out);
    }
}

// Round 4
// 304.184 us; speedup vs baseline: 1.1742x; 1.1742x over previous
//
#include <hip/hip_runtime.h>
#include <hip/hip_bf16.h>
#include <math.h>
#include <float.h>

#ifndef M_PI
#define M_PI 3.14159265358979323846
#endif

// Problem constants
#define NBANDS 160      // B*NB = 32*5
#define RR 96           // rows per band
#define TT 2048         // time samples
#define NTRIL 4560      // 96*95/2
#define A_ELEMS ((size_t)NBANDS * RR * RR)
#define NBIN 8192
#define MAXCAND 512
#define BKS 64          // K per stage
#define GPITCH 72       // LDS row pitch (bf16) for gram staging
#define FBLK 384        // fused kernel block size (6 waves)

// XOR bank swizzle for the FFT kernel
#define PHI(L) ((L) ^ (((L) >> 5) & 31))

typedef float  f32x4  __attribute__((ext_vector_type(4)));
typedef __bf16 bf16x8 __attribute__((ext_vector_type(8)));
typedef __bf16 bf16x4 __attribute__((ext_vector_type(4)));

// ---------- block reductions (any blockDim multiple of 64) ----------
__device__ inline void blockReduceSum4(double v0, double v1, double v2, double v3,
                                       double* sred, double out[4]) {
    for (int off = 32; off > 0; off >>= 1) {
        v0 += __shfl_down(v0, off, 64);
        v1 += __shfl_down(v1, off, 64);
        v2 += __shfl_down(v2, off, 64);
        v3 += __shfl_down(v3, off, 64);
    }
    int lane = threadIdx.x & 63, wid = threadIdx.x >> 6;
    int nw = blockDim.x >> 6;
    if (lane == 0) {
        sred[wid * 4 + 0] = v0; sred[wid * 4 + 1] = v1;
        sred[wid * 4 + 2] = v2; sred[wid * 4 + 3] = v3;
    }
    __syncthreads();
    if (threadIdx.x < 4) {
        double r = sred[threadIdx.x];
        for (int w = 1; w < nw; w++) r += sred[w * 4 + threadIdx.x];
        sred[nw * 4 + threadIdx.x] = r;
    }
    __syncthreads();
    out[0] = sred[nw * 4 + 0]; out[1] = sred[nw * 4 + 1];
    out[2] = sred[nw * 4 + 2]; out[3] = sred[nw * 4 + 3];
    __syncthreads();
}

__device__ inline void blockReduceSum2(double v0, double v1,
                                       double* sred, double out[2]) {
    for (int off = 32; off > 0; off >>= 1) {
        v0 += __shfl_down(v0, off, 64);
        v1 += __shfl_down(v1, off, 64);
    }
    int lane = threadIdx.x & 63, wid = threadIdx.x >> 6;
    int nw = blockDim.x >> 6;
    if (lane == 0) { sred[wid * 2 + 0] = v0; sred[wid * 2 + 1] = v1; }
    __syncthreads();
    if (threadIdx.x < 2) {
        double r = sred[threadIdx.x];
        for (int w = 1; w < nw; w++) r += sred[w * 2 + threadIdx.x];
        sred[nw * 2 + threadIdx.x] = r;
    }
    __syncthreads();
    out[0] = sred[nw * 2 + 0]; out[1] = sred[nw * 2 + 1];
    __syncthreads();
}

__device__ inline void blockReduceMax2(double v0, double v1,
                                       double* sred, double out[2]) {
    for (int off = 32; off > 0; off >>= 1) {
        v0 = fmax(v0, __shfl_down(v0, off, 64));
        v1 = fmax(v1, __shfl_down(v1, off, 64));
    }
    int lane = threadIdx.x & 63, wid = threadIdx.x >> 6;
    int nw = blockDim.x >> 6;
    if (lane == 0) { sred[wid * 2 + 0] = v0; sred[wid * 2 + 1] = v1; }
    __syncthreads();
    if (threadIdx.x < 2) {
        double r = sred[threadIdx.x];
        for (int w = 1; w < nw; w++) r = fmax(r, sred[w * 2 + threadIdx.x]);
        sred[nw * 2 + threadIdx.x] = r;
    }
    __syncthreads();
    out[0] = sred[nw * 2 + 0]; out[1] = sred[nw * 2 + 1];
    __syncthreads();
}

// ---------- K0: twiddle table  tw[k] = exp(-2*pi*i*k/2048), k<1024 (fp32) ----------
__global__ void twiddle_kernel(float* tw) {
    int k = blockIdx.x * blockDim.x + threadIdx.x;
    if (k < 1024) {
        double ang = -2.0 * M_PI * (double)k / 2048.0;
        tw[2 * k]     = (float)cos(ang);
        tw[2 * k + 1] = (float)sin(ang);
    }
}

// DIT butterfly on register pair (r1, r2) with twiddle (WR, WI)
#define BFLY(r1, r2, WR, WI) do { \
    float _wr = (WR), _wi = (WI); \
    float _tr = _wr * yr[r2] - _wi * yi[r2]; \
    float _ti = _wr * yi[r2] + _wi * yr[r2]; \
    yr[r2] = yr[r1] - _tr; yi[r2] = yi[r1] - _ti; \
    yr[r1] += _tr; yi[r1] += _ti; } while (0)

// ---------- K1: per-row stats + fp32 register radix-8 FFT entropy ----------
// Round-1 proven structure (94.5 us): 2 rows/block packed re/im, 16.9 KB LDS,
// f32 per-thread stats, batched reductions, __logf. Only change vs round 1:
// float2 twiddle loads (halves twiddle VMEM op count).
__global__ __launch_bounds__(256) void rowstat_fft_kernel(
    const float* __restrict__ wc, const float* __restrict__ tw,
    double* __restrict__ rowstats)
{
    __shared__ float re[TT];
    __shared__ float im[TT];
    __shared__ double sred[32];
    __shared__ float bcast[4];

    int t = threadIdx.x;
    int g0 = blockIdx.x * 2;
    int g1 = g0 + 1;

    int band = g0 / RR, r0 = g0 % RR;
    int b = band / 5, nb = band % 5;
    size_t base0 = ((size_t)(b * RR + r0) * 5 + nb) * TT;
    size_t base1 = base0 + (size_t)5 * TT;
    const float2* twv = (const float2*)tw;

    float s0 = 0.f, s1 = 0.f, q0 = 0.f, q1 = 0.f, m0 = 0.f, m1 = 0.f;
#pragma unroll
    for (int c = 0; c < 8; c++) {
        int i = t + c * 256;
        float af = wc[base0 + i];
        float bf = wc[base1 + i];
        int P = PHI(i);
        re[P] = af; im[P] = bf;
        s0 += af; s1 += bf;
        q0 = fmaf(af, af, q0); q1 = fmaf(bf, bf, q1);
        m0 = fmaxf(m0, fabsf(af)); m1 = fmaxf(m1, fabsf(bf));
    }
    __syncthreads();

    double S4[4], M2[2];
    blockReduceSum4((double)s0, (double)s1, (double)q0, (double)q1, sred, S4);
    blockReduceMax2((double)m0, (double)m1, sred, M2);
    double SUM0 = S4[0], SUM1 = S4[1], SQ0 = S4[2], SQ1 = S4[3];
    double MX0 = M2[0], MX1 = M2[1];

    float yr[8], yi[8];

#pragma unroll
    for (int j = 0; j < 8; j++) {
        int p = 8 * t + j;
        int L = (int)(__brev((unsigned)p) >> 21);
        int P = PHI(L);
        yr[j] = re[P]; yi[j] = im[P];
    }

    const float RC = 0.70710678f;
    BFLY(0, 1, 1.0f, 0.0f); BFLY(2, 3, 1.0f, 0.0f);
    BFLY(4, 5, 1.0f, 0.0f); BFLY(6, 7, 1.0f, 0.0f);
    BFLY(0, 2, 1.0f, 0.0f); BFLY(1, 3, 0.0f, -1.0f);
    BFLY(4, 6, 1.0f, 0.0f); BFLY(5, 7, 0.0f, -1.0f);
    BFLY(0, 4, 1.0f, 0.0f); BFLY(1, 5, RC, -RC);
    BFLY(2, 6, 0.0f, -1.0f); BFLY(3, 7, -RC, -RC);

    __syncthreads();
#pragma unroll
    for (int j = 0; j < 8; j++) {
        int P = PHI(8 * t + j);
        re[P] = yr[j]; im[P] = yi[j];
    }
    __syncthreads();
    int oo = t & 7;
    int bb64 = 4 * ((t >> 3) & 7) + (t >> 6);
#pragma unroll
    for (int k = 0; k < 8; k++) {
        int P = PHI(64 * bb64 + 8 * k + oo);
        yr[k] = re[P]; yi[k] = im[P];
    }

    {
        float2 w0 = twv[oo << 7];
        BFLY(0, 1, w0.x, w0.y); BFLY(2, 3, w0.x, w0.y);
        BFLY(4, 5, w0.x, w0.y); BFLY(6, 7, w0.x, w0.y);
        float2 wa = twv[oo << 6];
        float2 wb = twv[(oo + 8) << 6];
        BFLY(0, 2, wa.x, wa.y); BFLY(1, 3, wb.x, wb.y);
        BFLY(4, 6, wa.x, wa.y); BFLY(5, 7, wb.x, wb.y);
        float2 wc0 = twv[oo << 5], wc1 = twv[(oo + 8) << 5];
        float2 wc2 = twv[(oo + 16) << 5], wc3 = twv[(oo + 24) << 5];
        BFLY(0, 4, wc0.x, wc0.y);
        BFLY(1, 5, wc1.x, wc1.y);
        BFLY(2, 6, wc2.x, wc2.y);
        BFLY(3, 7, wc3.x, wc3.y);
    }

    __syncthreads();
#pragma unroll
    for (int k = 0; k < 8; k++) {
        int P = PHI(64 * bb64 + 8 * k + oo);
        re[P] = yr[k]; im[P] = yi[k];
    }
    __syncthreads();
    int O3 = t & 63, Wq = t >> 6;
#pragma unroll
    for (int s = 0; s < 2; s++) {
        int B3 = Wq + 4 * s;
#pragma unroll
        for (int k = 0; k < 4; k++) {
            int P = PHI(256 * B3 + 64 * k + O3);
            yr[4 * s + k] = re[P]; yi[4 * s + k] = im[P];
        }
    }

    {
        float2 w0 = twv[O3 << 4];
        float2 wa = twv[O3 << 3];
        float2 wb = twv[(O3 + 64) << 3];
        BFLY(0, 1, w0.x, w0.y); BFLY(2, 3, w0.x, w0.y);
        BFLY(4, 5, w0.x, w0.y); BFLY(6, 7, w0.x, w0.y);
        BFLY(0, 2, wa.x, wa.y); BFLY(1, 3, wb.x, wb.y);
        BFLY(4, 6, wa.x, wa.y); BFLY(5, 7, wb.x, wb.y);
    }

    __syncthreads();
#pragma unroll
    for (int s = 0; s < 2; s++) {
        int B3 = Wq + 4 * s;
#pragma unroll
        for (int k = 0; k < 4; k++) {
            int P = PHI(256 * B3 + 64 * k + O3);
            re[P] = yr[4 * s + k]; im[P] = yi[4 * s + k];
        }
    }
    __syncthreads();
#pragma unroll
    for (int k = 0; k < 8; k++) {
        int P = PHI(256 * k + t);
        yr[k] = re[P]; yi[k] = im[P];
    }

    {
        float2 w0 = twv[t << 2];
        float2 wa = twv[t << 1];
        float2 wb = twv[(t + 256) << 1];
        BFLY(0, 1, w0.x, w0.y); BFLY(2, 3, w0.x, w0.y);
        BFLY(4, 5, w0.x, w0.y); BFLY(6, 7, w0.x, w0.y);
        BFLY(0, 2, wa.x, wa.y); BFLY(1, 3, wb.x, wb.y);
        BFLY(4, 6, wa.x, wa.y); BFLY(5, 7, wb.x, wb.y);
        float2 wf0 = twv[t], wf1 = twv[t + 256];
        float2 wf2 = twv[t + 512], wf3 = twv[t + 768];
        BFLY(0, 4, wf0.x, wf0.y);
        BFLY(1, 5, wf1.x, wf1.y);
        BFLY(2, 6, wf2.x, wf2.y);
        BFLY(3, 7, wf3.x, wf3.y);
    }

    __syncthreads();
#pragma unroll
    for (int k = 0; k < 8; k++) {
        int P = PHI(256 * k + t);
        re[P] = yr[k]; im[P] = yi[k];
    }
    __syncthreads();

    float psa[8], psb[8];
#pragma unroll
    for (int k = 0; k < 8; k++) {
        int q = (2048 - t - 256 * k) & 2047;
        int P = PHI(q);
        float prr = re[P], pii = im[P];
        float sr = yr[k] + prr, di = yi[k] - pii;
        float si = yi[k] + pii, dr = yr[k] - prr;
        psa[k] = 0.25f * (sr * sr + di * di);
        psb[k] = 0.25f * (si * si + dr * dr);
    }

    float la = 0.f, lb = 0.f;
#pragma unroll
    for (int k = 0; k < 8; k++) { la += psa[k]; lb += psb[k]; }
    double SS[2];
    blockReduceSum2((double)la, (double)lb, sred, SS);
    double SAall = SS[0], SBall = SS[1];
    if (t == 0) {
        bcast[0] = psa[0]; bcast[1] = psa[4];
        bcast[2] = psb[0]; bcast[3] = psb[4];
    }
    __syncthreads();
    double Sa = 0.5 * (SAall + (double)bcast[0] - (double)bcast[1]);
    double Sb = 0.5 * (SBall + (double)bcast[2] - (double)bcast[3]);
    if (Sa == 0.0) Sa = 1.0;
    if (Sb == 0.0) Sb = 1.0;
    float invSa = (float)(1.0 / Sa), invSb = (float)(1.0 / Sb);

    float ea = 0.f, eb = 0.f;
#pragma unroll
    for (int k = 0; k < 8; k++) {
        float pa = psa[k] * invSa;
        float pb = psb[k] * invSb;
        ea += pa * __logf(pa + 1e-10f);
        eb += pb * __logf(pb + 1e-10f);
    }
    double EE[2];
    blockReduceSum2((double)ea, (double)eb, sred, EE);
    double EAall = EE[0], EBall = EE[1];

    if (t == 0) {
        float pa0 = psa[0] * invSa, pa4 = psa[4] * invSa;
        float pb0 = psb[0] * invSb, pb4 = psb[4] * invSb;
        double TA = 0.5 * (EAall + (double)(pa0 * __logf(pa0 + 1e-10f))
                                 - (double)(pa4 * __logf(pa4 + 1e-10f)));
        double TB = 0.5 * (EBall + (double)(pb0 * __logf(pb0 + 1e-10f))
                                 - (double)(pb4 * __logf(pb4 + 1e-10f)));
        double mean0 = SUM0 / (double)TT;
        double mean1 = SUM1 / (double)TT;
        double nsq0 = SQ0 - (double)TT * mean0 * mean0; if (nsq0 < 0) nsq0 = 0;
        double nsq1 = SQ1 - (double)TT * mean1 * mean1; if (nsq1 < 0) nsq1 = 0;
        double* w0 = rowstats + (size_t)g0 * 6;
        double* w1 = rowstats + (size_t)g1 * 6;
        double n0 = sqrt(nsq0), n1 = sqrt(nsq1);
        w0[0] = mean0; w0[1] = (n0 == 0.0 ? 1.0 : n0); w0[2] = sqrt(nsq0 / 2047.0);
        w0[3] = SQ0;   w0[4] = MX0;                    w0[5] = -TA;
        w1[0] = mean1; w1[1] = (n1 == 0.0 ? 1.0 : n1); w1[2] = sqrt(nsq1 / 2047.0);
        w1[3] = SQ1;   w1[4] = MX1;                    w1[5] = -TB;
    }
}

// fp32 -> hi/lo bf16 split into LDS staging tiles
#define CVW(v, row, c4) do { \
    __bf16 _h0 = (__bf16)v.x, _h1 = (__bf16)v.y, _h2 = (__bf16)v.z, _h3 = (__bf16)v.w; \
    __bf16 _l0 = (__bf16)(v.x - (float)_h0), _l1 = (__bf16)(v.y - (float)_h1); \
    __bf16 _l2 = (__bf16)(v.z - (float)_h2), _l3 = (__bf16)(v.w - (float)_h3); \
    *(bf16x4*)&sh_hi[row][(c4) * 4] = (bf16x4){_h0, _h1, _h2, _h3}; \
    *(bf16x4*)&sh_lo[row][(c4) * 4] = (bf16x4){_l0, _l1, _l2, _l3}; } while (0)

// ---------- K2: fused per-band gram + finalize ----------
// One block per band, 384 thr = 6 waves. K-loops all 2048 samples in 32
// stages of 64 (reg-staged prefetch: next stage's global loads issued before
// this stage's MFMA). Wave w owns rows [16w,16w+16) x all 96 cols; acc stays
// in VGPRs, is normalized in-register against rowstats, written to LDS Cs and
// histogrammed on the fly. Then: quantile select -> masked A write -> ballot
// bitmask graph props -> MLP -> F. No gram partials, no extra launches.
__global__ __launch_bounds__(FBLK) void fused_gram_finalize_kernel(
    const float* __restrict__ wc, const double* __restrict__ rowstats,
    const int* __restrict__ community,
    const float* __restrict__ W1, const float* __restrict__ b1,
    const float* __restrict__ W2, const float* __restrict__ b2,
    float* __restrict__ A_out, float* __restrict__ F_out)
{
    __shared__ __attribute__((aligned(16))) __bf16 sh_hi[RR][GPITCH];  // 13.5 KB
    __shared__ __attribute__((aligned(16))) __bf16 sh_lo[RR][GPITCH];  // 13.5 KB
    __shared__ float Cs[RR][RR];               // 36 KB
    __shared__ int hist[NBIN];                 // 32 KB
    __shared__ int chunkv[256];
    __shared__ float cand[MAXCAND];
    __shared__ int ctrl[4];
    __shared__ double mean_s[RR], inv_s[RR];
    __shared__ int comm_s[RR];
    __shared__ unsigned long long msk[RR][2];
    __shared__ int deg[RR];
    __shared__ double sred[32];
    __shared__ double feat[11];
    __shared__ double hmlp[32];
    __shared__ double thr_s;

    int band = blockIdx.x, t = threadIdx.x;
    int b = band / 5, nb = band % 5;
    size_t bandbase = ((size_t)b * RR * 5 + nb) * TT;
    const double* rsb = rowstats + (size_t)band * RR * 6;

    if (t < RR) {
        mean_s[t] = rsb[t * 6 + 0];
        inv_s[t]  = 1.0 / rsb[t * 6 + 1];
        comm_s[t] = community[t];
    }
    for (int i = t; i < NBIN; i += FBLK) hist[i] = 0;
    if (t == 0) ctrl[3] = 0;

    int wave = t >> 6, lane = t & 63;
    int m16 = lane & 15, quad = lane >> 4;
    int arow = wave * 16 + m16;

    // per-thread staging slots: gid = t + i*384 over 1536 = 96 rows x 16 float4
    int gid0 = t, gid1 = t + 384, gid2 = t + 768, gid3 = t + 1152;
    int row0 = gid0 >> 4, c40 = gid0 & 15;
    int row1 = gid1 >> 4, c41 = gid1 & 15;
    int row2 = gid2 >> 4, c42 = gid2 & 15;
    int row3 = gid3 >> 4, c43 = gid3 & 15;
    const float* p0 = wc + bandbase + (size_t)row0 * (5 * TT) + c40 * 4;
    const float* p1 = wc + bandbase + (size_t)row1 * (5 * TT) + c41 * 4;
    const float* p2 = wc + bandbase + (size_t)row2 * (5 * TT) + c42 * 4;
    const float* p3 = wc + bandbase + (size_t)row3 * (5 * TT) + c43 * 4;

    f32x4 acc[6];
#pragma unroll
    for (int ct = 0; ct < 6; ct++) acc[ct] = (f32x4){0.f, 0.f, 0.f, 0.f};

    float4 pr0 = *(const float4*)(p0);
    float4 pr1 = *(const float4*)(p1);
    float4 pr2 = *(const float4*)(p2);
    float4 pr3 = *(const float4*)(p3);

    for (int st = 0; st < TT / BKS; st++) {
        CVW(pr0, row0, c40); CVW(pr1, row1, c41);
        CVW(pr2, row2, c42); CVW(pr3, row3, c43);
        __syncthreads();
        if (st + 1 < TT / BKS) {
            int k0 = (st + 1) * BKS;
            pr0 = *(const float4*)(p0 + k0);
            pr1 = *(const float4*)(p1 + k0);
            pr2 = *(const float4*)(p2 + k0);
            pr3 = *(const float4*)(p3 + k0);
        }
#pragma unroll
        for (int ks = 0; ks < BKS / 32; ks++) {
            int ko = ks * 32 + quad * 8;
            bf16x8 ah = *(const bf16x8*)&sh_hi[arow][ko];
            bf16x8 al = *(const bf16x8*)&sh_lo[arow][ko];
#pragma unroll
            for (int ct = 0; ct < 6; ct++) {
                int brow = ct * 16 + m16;
                bf16x8 bh = *(const bf16x8*)&sh_hi[brow][ko];
                bf16x8 bl = *(const bf16x8*)&sh_lo[brow][ko];
                acc[ct] = __builtin_amdgcn_mfma_f32_16x16x32_bf16(ah, bh, acc[ct], 0, 0, 0);
                acc[ct] = __builtin_amdgcn_mfma_f32_16x16x32_bf16(ah, bl, acc[ct], 0, 0, 0);
                acc[ct] = __builtin_amdgcn_mfma_f32_16x16x32_bf16(al, bh, acc[ct], 0, 0, 0);
            }
        }
        __syncthreads();
    }

    // epilogue: normalize in-register, write Cs, histogram tril on the fly
#pragma unroll
    for (int ct = 0; ct < 6; ct++) {
#pragma unroll
        for (int r = 0; r < 4; r++) {
            int grow = wave * 16 + quad * 4 + r;
            int gcol = ct * 16 + m16;
            double cd = ((double)acc[ct][r]
                         - (double)TT * mean_s[grow] * mean_s[gcol])
                        * (inv_s[grow] * inv_s[gcol]);
            if (grow == gcol) cd = 0.0;
            float cf = (float)cd;
            Cs[grow][gcol] = cf;
            if (gcol < grow) {
                float val = fabsf(cf);
                int bin = (int)(val * (float)NBIN);
                bin = bin > (NBIN - 1) ? (NBIN - 1) : bin;
                atomicAdd(&hist[bin], 1);
            }
        }
    }
    __syncthreads();

    // quantile select: 256 chunks of 32 bins
    if (t < 256) {
        int cs = 0;
        for (int i = 0; i < NBIN / 256; i++) cs += hist[t * (NBIN / 256) + i];
        chunkv[t] = cs;
    }
    __syncthreads();

    if (t == 0) {
        int r0 = 3647, r1 = 3648;
        int cum = 0, c0 = 0;
        while (c0 < 256 && cum + chunkv[c0] <= r0) { cum += chunkv[c0]; c0++; }
        int bin = c0 * (NBIN / 256), cb = cum;
        while (cb + hist[bin] <= r0) { cb += hist[bin]; bin++; }
        int B0 = bin, cumB0 = cb;
        int bin1 = bin, cb1 = cb;
        while (cb1 + hist[bin1] <= r1) { cb1 += hist[bin1]; bin1++; }
        ctrl[0] = B0; ctrl[1] = bin1; ctrl[2] = cumB0;
    }
    __syncthreads();

    int B0 = ctrl[0], B1 = ctrl[1];
    for (int idx = t; idx < RR * RR; idx += FBLK) {
        int i = idx / RR, j = idx % RR;
        if (j < i) {
            float val = fabsf(Cs[i][j]);
            int bin = (int)(val * (float)NBIN);
            bin = bin > (NBIN - 1) ? (NBIN - 1) : bin;
            if (bin >= B0 && bin <= B1) {
                int k = atomicAdd(&ctrl[3], 1);
                if (k < MAXCAND) cand[k] = val;
            }
        }
    }
    __syncthreads();

    if (t == 0) {
        int n = ctrl[3]; if (n > MAXCAND) n = MAXCAND;
        for (int i = 1; i < n; i++) {
            float key = cand[i]; int j = i - 1;
            while (j >= 0 && cand[j] > key) { cand[j + 1] = cand[j]; j--; }
            cand[j + 1] = key;
        }
        int r0 = 3647 - ctrl[2];
        int r1 = 3648 - ctrl[2];
        double v0 = (double)cand[r0], v1 = (double)cand[r1];
        thr_s = v0 + 0.2 * (v1 - v0);       // pos = 0.8*(4560-1) = 3647.2
    }
    __syncthreads();
    double thr = thr_s;

    // masked A write (single pass, coalesced)
    float* Ab = A_out + (size_t)band * (RR * RR);
    for (int idx = t; idx < RR * RR; idx += FBLK) {
        float cf = Cs[idx / RR][idx % RR];
        bool keep = ((double)fabsf(cf) >= thr);
        Ab[idx] = keep ? cf : 0.f;
    }

    // adjacency bitmasks via ballot: wave w handles rows w, w+6, ...
    for (int i = wave; i < RR; i += 6) {
        float vlo = Cs[i][lane];
        bool klo = ((double)fabsf(vlo) >= thr) && (vlo != 0.f);
        unsigned long long blo = __ballot(klo);
        float vhi = Cs[i][64 + (lane & 31)];
        bool khi = (lane < 32) && ((double)fabsf(vhi) >= thr) && (vhi != 0.f);
        unsigned long long bhi = __ballot(khi) & 0xffffffffull;
        if (lane == 0) {
            msk[i][0] = blo; msk[i][1] = bhi;
            deg[i] = __popcll(blo) + __popcll(bhi);
        }
    }
    __syncthreads();

    double triord = 0, ein = 0, expin = 0;
    for (int idx = t; idx < RR * RR; idx += FBLK) {
        int i = idx / RR, j = idx % RR;
        unsigned long long mi0 = msk[i][0], mi1 = msk[i][1];
        bool bij = (((j < 64) ? (mi0 >> j) : (mi1 >> (j - 64))) & 1ull) != 0;
        if (bij)
            triord += (double)(__popcll(mi0 & msk[j][0]) +
                               __popcll(mi1 & msk[j][1]));
        if (i != j && comm_s[i] == comm_s[j]) {
            ein += bij ? 1.0 : 0.0;
            expin += (double)deg[i] * (double)deg[j];
        }
    }
    double dv = (t < RR) ? (double)deg[t] : 0.0;
    double R1[4], R2[4], R3[2];
    blockReduceSum4(triord, ein, expin, dv, sred, R1);
    blockReduceSum4((t < RR) ? dv * (dv - 1.0) : 0.0,
                    (t < RR) ? rsb[t * 6 + 0] : 0.0,
                    (t < RR) ? rsb[t * 6 + 2] : 0.0,
                    (t < RR) ? rsb[t * 6 + 3] : 0.0, sred, R2);
    blockReduceSum2((t < RR) ? rsb[t * 6 + 4] : 0.0,
                    (t < RR) ? rsb[t * 6 + 5] : 0.0, sred, R3);
    double TRI = R1[0], EIN = R1[1], EXPIN = R1[2], DEGS = R1[3];
    double POSS2 = R2[0], N0 = R2[1], N1 = R2[2], N2 = R2[3];
    double N3 = R3[0], N4 = R3[1];

    if (t == 0) {
        double ne = 0.5 * DEGS;
        feat[0] = N0 / (double)RR;
        feat[1] = N1 / (double)RR;
        feat[2] = N2 / (double)RR;
        feat[3] = N3 / (double)RR;
        feat[4] = N4 / (double)RR;
        feat[5] = ne;
        feat[6] = ne / (double)NTRIL;
        feat[7] = DEGS / (double)RR;
        double tri = TRI / 6.0, poss = POSS2 * 0.5;
        feat[8] = (poss > 0.0) ? tri / poss : 0.0;
        feat[9] = ((double)RR + DEGS) / ((double)RR * (double)(RR - 1));
        double m2 = DEGS;
        feat[10] = (m2 > 0.0) ? (EIN - EXPIN / m2) / m2 : 0.0;
    }
    __syncthreads();

    if (t < 32) {
        double a = (double)b1[t];
        for (int k = 0; k < 11; k++) a += (double)W1[t * 11 + k] * feat[k];
        hmlp[t] = (a > 0.0) ? a : 0.0;
    }
    __syncthreads();
    if (t < 64) {
        double a = (double)b2[t];
        for (int j = 0; j < 32; j++) a += (double)W2[t * 32 + j] * hmlp[j];
        F_out[(size_t)band * 64 + t] = (float)a;
    }
}

extern "C" void kernel_launch(void* const* d_in, const int* in_sizes, int n_in,
                              void* d_out, int out_size, void* d_ws, size_t ws_size,
                              hipStream_t stream) {
    const float* wc        = (const float*)d_in[0];
    // d_in[1] frequency_bands: unused by the reference math
    const int*   community = (const int*)d_in[2];
    const float* W1        = (const float*)d_in[3];
    const float* b1        = (const float*)d_in[4];
    const float* W2        = (const float*)d_in[5];
    const float* b2        = (const float*)d_in[6];

    float* A_out = (float*)d_out;
    float* F_out = A_out + A_ELEMS;

    // workspace layout: tw @ 0 (8192 B) | rowstats @ 8192 (15360*6*8 = 737280 B)
    char* ws = (char*)d_ws;
    float*  tw       = (float*)ws;
    double* rowstats = (double*)(ws + 8192);

    hipLaunchKernelGGL(twiddle_kernel, dim3(4), dim3(256), 0, stream, tw);
    hipLaunchKernelGGL(rowstat_fft_kernel, dim3(NBANDS * RR / 2), dim3(256), 0, stream,
                       wc, tw, rowstats);
    hipLaunchKernelGGL(fused_gram_finalize_kernel, dim3(NBANDS), dim3(FBLK), 0, stream,
                       wc, rowstats, community, W1, b1, W2, b2, A_out, F_out);
}